// Round 16
// baseline (312.988 us; speedup 1.0000x reference)
//
#include <hip/hip_runtime.h>
#include <hip/hip_fp16.h>
#include <math.h>

// GraphSAGE 2-layer, N=100000, E=3200000; IN=128, H1=32, H2=20, NCLS=10
// r16 = r15 frozen + ONE probe: k_agg2's table gather uses agent-scope
// relaxed loads (global_load_ushort sc0 -> bypasses L1 allocation/MSHR,
// normal L2). Tests the "per-CU L1-MSHR ~32 outstanding" wall hypothesis.
// k_agg1 = plain-load control (98us / 105MB reference).

#define BSHIFT 7
#define BS_NODES 128
#define PART_TILE 8192

__device__ __forceinline__ unsigned pk(float a, float b) {
    __half2 h = __floats2half2_rn(a, b);
    return *reinterpret_cast<unsigned*>(&h);
}

__device__ __forceinline__ float h2f_bits(unsigned short u) {
    __half_raw hr; hr.x = u;
    return __half2float(__half(hr));
}

// ---- stage 1: partition edges into per-bucket regions (cursors = counts) ----
__global__ __launch_bounds__(256) void k_part(
    const int* __restrict__ src, const int* __restrict__ dst,
    int* __restrict__ bcursor, int* __restrict__ pairs,
    int n_edges, int nb, int capb)
{
    __shared__ int cnt[1024];
    __shared__ int bbase_l[1024];
    int tid = threadIdx.x;
    int ebeg = blockIdx.x * PART_TILE;
    int eend = ebeg + PART_TILE; if (eend > n_edges) eend = n_edges;
    for (int i = tid; i < nb; i += 256) cnt[i] = 0;
    __syncthreads();
    for (int e = ebeg + tid; e < eend; e += 256)
        atomicAdd(&cnt[dst[e] >> BSHIFT], 1);
    __syncthreads();
    for (int i = tid; i < nb; i += 256) {
        int c = cnt[i];
        if (c > 0) bbase_l[i] = atomicAdd(&bcursor[i], c);
    }
    __syncthreads();
    for (int e = ebeg + tid; e < eend; e += 256) {
        int d = dst[e];
        int b = d >> BSHIFT;
        int slot = atomicSub(&cnt[b], 1) - 1;     // countdown ticket
        pairs[(size_t)b * capb + bbase_l[b] + slot] =
            (src[e] << BSHIFT) | (d & (BS_NODES - 1));
    }
}

// ---- stage 2: per-bucket fill of eid + int2 extents (no global scan) ----
__global__ __launch_bounds__(256) void k_bfill(
    const int* __restrict__ pairs, const int* __restrict__ bcursor,
    int2* __restrict__ row2, int* __restrict__ eid,
    int capb, int n_nodes)
{
    __shared__ int cnt128[BS_NODES];
    __shared__ int sc[BS_NODES];
    __shared__ int cur[BS_NODES];
    int b = blockIdx.x;
    int tid = threadIdx.x;
    int lo = b * BS_NODES;
    size_t base = (size_t)b * capb;
    int cntE = bcursor[b];
    if (tid < BS_NODES) cnt128[tid] = 0;
    __syncthreads();
    for (int i = tid; i < cntE; i += 256)
        atomicAdd(&cnt128[pairs[base + i] & (BS_NODES - 1)], 1);
    __syncthreads();
    int myc = 0;
    if (tid < BS_NODES) { myc = cnt128[tid]; sc[tid] = myc; }
    __syncthreads();
    for (int off = 1; off < BS_NODES; off <<= 1) {
        int v = (tid >= off && tid < BS_NODES) ? sc[tid - off] : 0;
        __syncthreads();
        if (tid < BS_NODES) sc[tid] += v;
        __syncthreads();
    }
    if (tid < BS_NODES) {
        int excl = sc[tid] - myc;
        cur[tid] = excl;
        if (lo + tid < n_nodes)
            row2[lo + tid] = make_int2((int)base + excl,
                                       (int)base + excl + myc);
    }
    __syncthreads();
    for (int i = tid; i < cntE; i += 256) {
        int p = pairs[base + i];
        int pos = atomicAdd(&cur[p & (BS_NODES - 1)], 1);
        eid[base + pos] = p >> BSHIFT;
    }
}

// ---- lin1: TWO-PHASE 32KB LDS staging, thread-per-node, fp16 outputs ----
__global__ __launch_bounds__(256) void k_lin1(
    const float* __restrict__ x, const float* __restrict__ W1l,
    const float* __restrict__ b1, const float* __restrict__ W1r,
    __half* __restrict__ y1, __half* __restrict__ r1, int n_nodes)
{
    __shared__ unsigned lds[256 * 32];   // 32KB: 256 rows x 64 halfs
    int tid = threadIdx.x;
    int base = blockIdx.x * 256;
    const float4* x4 = reinterpret_cast<const float4*>(x);
    float accL[32], accR[32];
#pragma unroll
    for (int j = 0; j < 32; ++j) { accL[j] = 0.f; accR[j] = 0.f; }

    for (int ph = 0; ph < 2; ++ph) {
#pragma unroll
        for (int it = 0; it < 16; ++it) {
            int f = it * 256 + tid;
            int row = f >> 4, c4l = f & 15;
            int node = base + row;
            float4 v = make_float4(0.f, 0.f, 0.f, 0.f);
            if (node < n_nodes) v = x4[(size_t)node * 32 + ph * 16 + c4l];
            int kk = c4l * 2;
            lds[row * 32 + ((kk + row) & 31)]     = pk(v.x, v.y);
            lds[row * 32 + ((kk + 1 + row) & 31)] = pk(v.z, v.w);
        }
        __syncthreads();
        const unsigned* rb = &lds[tid * 32];
        for (int kk = 0; kk < 32; ++kk) {
            unsigned u = rb[(kk + tid) & 31];
            __half2 hh = *reinterpret_cast<__half2*>(&u);
            float2 f = __half22float2(hh);
            const float* wl = W1l + (ph * 32 + kk) * 64;
            const float* wr = W1r + (ph * 32 + kk) * 64;
#pragma unroll
            for (int j = 0; j < 32; ++j) {
                float a = accL[j];
                a = fmaf(f.x, wl[j],      a);
                a = fmaf(f.y, wl[32 + j], a);
                accL[j] = a;
                float c = accR[j];
                c = fmaf(f.x, wr[j],      c);
                c = fmaf(f.y, wr[32 + j], c);
                accR[j] = c;
            }
        }
        __syncthreads();
    }

    int node = base + tid;
    if (node < n_nodes) {
        unsigned o[16];
#pragma unroll
        for (int q = 0; q < 16; ++q) o[q] = pk(accL[2*q], accL[2*q+1]);
        uint4* yo = reinterpret_cast<uint4*>(y1 + (size_t)node * 32);
#pragma unroll
        for (int q = 0; q < 4; ++q)
            yo[q] = make_uint4(o[4*q], o[4*q+1], o[4*q+2], o[4*q+3]);
#pragma unroll
        for (int q = 0; q < 16; ++q)
            o[q] = pk(accR[2*q] + b1[2*q], accR[2*q+1] + b1[2*q+1]);
        uint4* ro = reinterpret_cast<uint4*>(r1 + (size_t)node * 32);
#pragma unroll
        for (int q = 0; q < 4; ++q)
            ro[q] = make_uint4(o[4*q], o[4*q+1], o[4*q+2], o[4*q+3]);
    }
}

// ---- gather-sum, 8 independent chains; SC0 = agent-scope (L1-bypass) ----
template <bool SC0>
__device__ __forceinline__ float gather_sum(
    const int* __restrict__ eid, const __half* __restrict__ tab,
    int beg, int end, int ch)
{
    const unsigned short* tb = reinterpret_cast<const unsigned short*>(tab);
    float s0 = 0.f, s1 = 0.f, s2 = 0.f, s3 = 0.f;
    float s4 = 0.f, s5 = 0.f, s6 = 0.f, s7 = 0.f;
#define LD(e) h2f_bits(SC0 ? __hip_atomic_load(&tb[(size_t)(e) * 32 + ch], \
                                 __ATOMIC_RELAXED, __HIP_MEMORY_SCOPE_AGENT) \
                           : tb[(size_t)(e) * 32 + ch])
    int i = beg;
    for (; i + 8 <= end; i += 8) {
        int e0 = eid[i];
        int e1 = eid[i + 1];
        int e2 = eid[i + 2];
        int e3 = eid[i + 3];
        int e4 = eid[i + 4];
        int e5 = eid[i + 5];
        int e6 = eid[i + 6];
        int e7 = eid[i + 7];
        s0 += LD(e0);
        s1 += LD(e1);
        s2 += LD(e2);
        s3 += LD(e3);
        s4 += LD(e4);
        s5 += LD(e5);
        s6 += LD(e6);
        s7 += LD(e7);
    }
    for (; i + 4 <= end; i += 4) {
        int e0 = eid[i];
        int e1 = eid[i + 1];
        int e2 = eid[i + 2];
        int e3 = eid[i + 3];
        s0 += LD(e0);
        s1 += LD(e1);
        s2 += LD(e2);
        s3 += LD(e3);
    }
    for (; i < end; ++i) {
        int e = eid[i];
        s0 += LD(e);
    }
#undef LD
    return ((s0 + s1) + (s2 + s3)) + ((s4 + s5) + (s6 + s7));
}

// ---- Layer 1: plain gather (CONTROL), combine, norm, relu, project ----
__global__ __launch_bounds__(256) void k_agg1(
    const int2* __restrict__ row2, const int* __restrict__ eid,
    const __half* __restrict__ y1, const __half* __restrict__ r1,
    const float* __restrict__ W2l, const float* __restrict__ W2r,
    const float* __restrict__ b2,
    __half* __restrict__ z2, __half* __restrict__ r2, int n_nodes)
{
    int t = blockIdx.x * 256 + threadIdx.x;
    int n = t >> 5;
    int ch = t & 31;
    if (n >= n_nodes) return;
    int2 be = row2[n];
    float sum = gather_sum<false>(eid, y1, be.x, be.y, ch);
    float inv = 1.0f / fmaxf((float)(be.y - be.x), 1.0f);
    float v = fmaf(sum, inv, __half2float(r1[(size_t)n * 32 + ch]));
    float ss = v * v;
#pragma unroll
    for (int off = 16; off >= 1; off >>= 1) ss += __shfl_xor(ss, off, 32);
    float h = fmaxf(v / fmaxf(sqrtf(ss), 1e-12f), 0.f);
    float accl = 0.f, accr = 0.f;
#pragma unroll 4
    for (int ii = 0; ii < 32; ++ii) {
        float hv = __shfl(h, ii, 32);
        if (ch < 20) {
            accl = fmaf(hv, W2l[ii * 20 + ch], accl);
            accr = fmaf(hv, W2r[ii * 20 + ch], accr);
        }
    }
    z2[(size_t)n * 32 + ch] = __float2half(ch < 20 ? accl : 0.f);
    r2[(size_t)n * 32 + ch] = __float2half(ch < 20 ? accr + b2[ch] : 0.f);
}

// ---- Layer 2: SC0 gather (PROBE), combine, norm, W_out, softmax ----
__global__ __launch_bounds__(256) void k_agg2(
    const int2* __restrict__ row2, const int* __restrict__ eid,
    const __half* __restrict__ z2, const __half* __restrict__ r2,
    const float* __restrict__ Wout, const float* __restrict__ bout,
    float* __restrict__ out, int n_nodes)
{
    int t = blockIdx.x * 256 + threadIdx.x;
    int n = t >> 5;
    int ch = t & 31;
    if (n >= n_nodes) return;
    int2 be = row2[n];
    bool act = ch < 20;
    float sum = gather_sum<true>(eid, z2, be.x, be.y, ch);
    float inv = 1.0f / fmaxf((float)(be.y - be.x), 1.0f);
    float v = act ? fmaf(sum, inv, __half2float(r2[(size_t)n * 32 + ch])) : 0.f;
    float ss = v * v;
#pragma unroll
    for (int off = 16; off >= 1; off >>= 1) ss += __shfl_xor(ss, off, 32);
    float o = v / fmaxf(sqrtf(ss), 1e-12f);
    float acc = (ch < 10) ? bout[ch] : 0.f;
#pragma unroll 4
    for (int ii = 0; ii < 20; ++ii) {
        float ov = __shfl(o, ii, 32);
        if (ch < 10) acc = fmaf(ov, Wout[ii * 10 + ch], acc);
    }
    float lm = (ch < 10) ? acc : -1e30f;
    float m = lm;
#pragma unroll
    for (int off = 8; off >= 1; off >>= 1) m = fmaxf(m, __shfl_xor(m, off, 16));
    float ex = (ch < 10) ? expf(acc - m) : 0.f;
    float s2r = ex;
#pragma unroll
    for (int off = 8; off >= 1; off >>= 1) s2r += __shfl_xor(s2r, off, 16);
    if (ch < 10) out[(size_t)n * 10 + ch] = ex / s2r;
}

extern "C" void kernel_launch(void* const* d_in, const int* in_sizes, int n_in,
                              void* d_out, int out_size, void* d_ws, size_t ws_size,
                              hipStream_t stream)
{
    const float* x    = (const float*)d_in[0];
    const int*   ei   = (const int*)d_in[1];
    const float* W1l  = (const float*)d_in[2];
    const float* b1   = (const float*)d_in[3];
    const float* W1r  = (const float*)d_in[4];
    const float* W2l  = (const float*)d_in[5];
    const float* b2   = (const float*)d_in[6];
    const float* W2r  = (const float*)d_in[7];
    const float* Wout = (const float*)d_in[8];
    const float* bout = (const float*)d_in[9];
    float* out = (float*)d_out;

    int n_nodes = in_sizes[0] / 128;
    int n_edges = in_sizes[1] / 2;
    const int* src = ei;
    const int* dst = ei + n_edges;

    int nb = (n_nodes + BS_NODES - 1) / BS_NODES;   // 782 (<= 1024)
    double mean = (double)n_edges / nb;
    int capb = (int)(mean + 8.0 * sqrt(mean) + 64.0);
    capb = (capb + 63) & ~63;

    // workspace: bcursor | row2 | pairs | eid | y1 | r1 ; z2/r2 alias pairs
    int*  bcursor = (int*)d_ws;                         // nb (memset to 0)
    int2* row2    = (int2*)((char*)d_ws + (((size_t)nb * 4 + 15) & ~(size_t)15)); // N int2
    int*  pairs   = (int*)(row2 + n_nodes);             // nb*capb
    size_t npairs = ((size_t)nb * capb + 3) & ~(size_t)3;
    int*  eid     = pairs + npairs;                     // nb*capb
    __half* y1 = (__half*)(eid + npairs);               // N*32 halfs
    __half* r1 = y1 + (size_t)n_nodes * 32;             // N*32 halfs (b1 folded)
    __half* z2 = (__half*)pairs;                        // alias: pairs dead after bfill
    __half* r2 = z2 + (size_t)n_nodes * 32;             // N*32 halfs (b2 folded)

    int nb_part = (n_edges + PART_TILE - 1) / PART_TILE;
    int nbl     = (n_nodes + 255) / 256;
    int nb_grp  = ((n_nodes * 32) + 255) / 256;

    (void)hipMemsetAsync(bcursor, 0, (size_t)nb * sizeof(int), stream);
    k_part<<<nb_part, 256, 0, stream>>>(src, dst, bcursor, pairs, n_edges, nb, capb);
    k_bfill<<<nb, 256, 0, stream>>>(pairs, bcursor, row2, eid, capb, n_nodes);
    k_lin1<<<nbl, 256, 0, stream>>>(x, W1l, b1, W1r, y1, r1, n_nodes);
    k_agg1<<<nb_grp, 256, 0, stream>>>(row2, eid, y1, r1, W2l, W2r, b2, z2, r2, n_nodes);
    k_agg2<<<nb_grp, 256, 0, stream>>>(row2, eid, z2, r2, Wout, bout, out, n_nodes);
}

// Round 17
// 293.808 us; speedup vs baseline: 1.0653x; 1.0653x over previous
//
#include <hip/hip_runtime.h>
#include <hip/hip_fp16.h>
#include <math.h>

// GraphSAGE 2-layer, N=100000, E=3200000; IN=128, H1=32, H2=20, NCLS=10
// r17 = r15 + k_part/k_lin1 FUSED (independent; 32KB LDS union; both
// branches small-grid so no occupancy starvation — unlike r13's 64KB
// bfill fusion). SC0 probe reverted (r16: flat -> wall is request-
// throughput structural; agg kernels frozen at ~183us floor).

#define BSHIFT 7
#define BS_NODES 128
#define PART_TILE 8192

__device__ __forceinline__ unsigned pk(float a, float b) {
    __half2 h = __floats2half2_rn(a, b);
    return *reinterpret_cast<unsigned*>(&h);
}

// ---- fused stage 1: blocks [0,nb_part) partition edges; rest do lin1 ----
__global__ __launch_bounds__(256) void k_partlin(
    const int* __restrict__ src, const int* __restrict__ dst,
    int* __restrict__ bcursor, int* __restrict__ pairs,
    const float* __restrict__ x, const float* __restrict__ W1l,
    const float* __restrict__ b1, const float* __restrict__ W1r,
    __half* __restrict__ y1, __half* __restrict__ r1,
    int n_edges, int nb, int capb, int n_nodes, int nb_part)
{
    __shared__ unsigned lds[256 * 32];   // 32KB union
    int tid = threadIdx.x;
    if ((int)blockIdx.x < nb_part) {
        // ---------------- edge-partition branch ----------------
        int* cnt     = (int*)lds;        // nb (<=1024)
        int* bbase_l = cnt + 1024;       // nb
        int ebeg = blockIdx.x * PART_TILE;
        int eend = ebeg + PART_TILE; if (eend > n_edges) eend = n_edges;
        for (int i = tid; i < nb; i += 256) cnt[i] = 0;
        __syncthreads();
        for (int e = ebeg + tid; e < eend; e += 256)
            atomicAdd(&cnt[dst[e] >> BSHIFT], 1);
        __syncthreads();
        for (int i = tid; i < nb; i += 256) {
            int c = cnt[i];
            if (c > 0) bbase_l[i] = atomicAdd(&bcursor[i], c);
        }
        __syncthreads();
        for (int e = ebeg + tid; e < eend; e += 256) {
            int d = dst[e];
            int b = d >> BSHIFT;
            int slot = atomicSub(&cnt[b], 1) - 1;     // countdown ticket
            pairs[(size_t)b * capb + bbase_l[b] + slot] =
                (src[e] << BSHIFT) | (d & (BS_NODES - 1));
        }
    } else {
        // ---------------- lin1 branch (two-phase 32KB staging) ----------------
        int base = ((int)blockIdx.x - nb_part) * 256;
        const float4* x4 = reinterpret_cast<const float4*>(x);
        float accL[32], accR[32];
#pragma unroll
        for (int j = 0; j < 32; ++j) { accL[j] = 0.f; accR[j] = 0.f; }
        for (int ph = 0; ph < 2; ++ph) {
#pragma unroll
            for (int it = 0; it < 16; ++it) {
                int f = it * 256 + tid;
                int row = f >> 4, c4l = f & 15;
                int node = base + row;
                float4 v = make_float4(0.f, 0.f, 0.f, 0.f);
                if (node < n_nodes) v = x4[(size_t)node * 32 + ph * 16 + c4l];
                int kk = c4l * 2;
                lds[row * 32 + ((kk + row) & 31)]     = pk(v.x, v.y);
                lds[row * 32 + ((kk + 1 + row) & 31)] = pk(v.z, v.w);
            }
            __syncthreads();
            const unsigned* rb = &lds[tid * 32];
            for (int kk = 0; kk < 32; ++kk) {
                unsigned u = rb[(kk + tid) & 31];
                __half2 hh = *reinterpret_cast<__half2*>(&u);
                float2 f = __half22float2(hh);
                const float* wl = W1l + (ph * 32 + kk) * 64;  // wave-uniform
                const float* wr = W1r + (ph * 32 + kk) * 64;
#pragma unroll
                for (int j = 0; j < 32; ++j) {
                    float a = accL[j];
                    a = fmaf(f.x, wl[j],      a);
                    a = fmaf(f.y, wl[32 + j], a);
                    accL[j] = a;
                    float c = accR[j];
                    c = fmaf(f.x, wr[j],      c);
                    c = fmaf(f.y, wr[32 + j], c);
                    accR[j] = c;
                }
            }
            __syncthreads();
        }
        int node = base + tid;
        if (node < n_nodes) {
            unsigned o[16];
#pragma unroll
            for (int q = 0; q < 16; ++q) o[q] = pk(accL[2*q], accL[2*q+1]);
            uint4* yo = reinterpret_cast<uint4*>(y1 + (size_t)node * 32);
#pragma unroll
            for (int q = 0; q < 4; ++q)
                yo[q] = make_uint4(o[4*q], o[4*q+1], o[4*q+2], o[4*q+3]);
#pragma unroll
            for (int q = 0; q < 16; ++q)
                o[q] = pk(accR[2*q] + b1[2*q], accR[2*q+1] + b1[2*q+1]);
            uint4* ro = reinterpret_cast<uint4*>(r1 + (size_t)node * 32);
#pragma unroll
            for (int q = 0; q < 4; ++q)
                ro[q] = make_uint4(o[4*q], o[4*q+1], o[4*q+2], o[4*q+3]);
        }
    }
}

// ---- stage 2: per-bucket fill of eid + int2 extents (no global scan) ----
__global__ __launch_bounds__(256) void k_bfill(
    const int* __restrict__ pairs, const int* __restrict__ bcursor,
    int2* __restrict__ row2, int* __restrict__ eid,
    int capb, int n_nodes)
{
    __shared__ int cnt128[BS_NODES];
    __shared__ int sc[BS_NODES];
    __shared__ int cur[BS_NODES];
    int b = blockIdx.x;
    int tid = threadIdx.x;
    int lo = b * BS_NODES;
    size_t base = (size_t)b * capb;
    int cntE = bcursor[b];
    if (tid < BS_NODES) cnt128[tid] = 0;
    __syncthreads();
    for (int i = tid; i < cntE; i += 256)
        atomicAdd(&cnt128[pairs[base + i] & (BS_NODES - 1)], 1);
    __syncthreads();
    int myc = 0;
    if (tid < BS_NODES) { myc = cnt128[tid]; sc[tid] = myc; }
    __syncthreads();
    for (int off = 1; off < BS_NODES; off <<= 1) {
        int v = (tid >= off && tid < BS_NODES) ? sc[tid - off] : 0;
        __syncthreads();
        if (tid < BS_NODES) sc[tid] += v;
        __syncthreads();
    }
    if (tid < BS_NODES) {
        int excl = sc[tid] - myc;
        cur[tid] = excl;
        if (lo + tid < n_nodes)
            row2[lo + tid] = make_int2((int)base + excl,
                                       (int)base + excl + myc);
    }
    __syncthreads();
    for (int i = tid; i < cntE; i += 256) {
        int p = pairs[base + i];
        int pos = atomicAdd(&cur[p & (BS_NODES - 1)], 1);
        eid[base + pos] = p >> BSHIFT;
    }
}

// ---- gather-sum over [beg,end): 8 independent chains, cached loads ----
__device__ __forceinline__ float gather_sum(
    const int* __restrict__ eid, const __half* __restrict__ tab,
    int beg, int end, int ch)
{
    float s0 = 0.f, s1 = 0.f, s2 = 0.f, s3 = 0.f;
    float s4 = 0.f, s5 = 0.f, s6 = 0.f, s7 = 0.f;
    int i = beg;
    for (; i + 8 <= end; i += 8) {
        int e0 = eid[i];
        int e1 = eid[i + 1];
        int e2 = eid[i + 2];
        int e3 = eid[i + 3];
        int e4 = eid[i + 4];
        int e5 = eid[i + 5];
        int e6 = eid[i + 6];
        int e7 = eid[i + 7];
        s0 += __half2float(tab[(size_t)e0 * 32 + ch]);
        s1 += __half2float(tab[(size_t)e1 * 32 + ch]);
        s2 += __half2float(tab[(size_t)e2 * 32 + ch]);
        s3 += __half2float(tab[(size_t)e3 * 32 + ch]);
        s4 += __half2float(tab[(size_t)e4 * 32 + ch]);
        s5 += __half2float(tab[(size_t)e5 * 32 + ch]);
        s6 += __half2float(tab[(size_t)e6 * 32 + ch]);
        s7 += __half2float(tab[(size_t)e7 * 32 + ch]);
    }
    for (; i + 4 <= end; i += 4) {
        int e0 = eid[i];
        int e1 = eid[i + 1];
        int e2 = eid[i + 2];
        int e3 = eid[i + 3];
        s0 += __half2float(tab[(size_t)e0 * 32 + ch]);
        s1 += __half2float(tab[(size_t)e1 * 32 + ch]);
        s2 += __half2float(tab[(size_t)e2 * 32 + ch]);
        s3 += __half2float(tab[(size_t)e3 * 32 + ch]);
    }
    for (; i < end; ++i) {
        int e = eid[i];
        s0 += __half2float(tab[(size_t)e * 32 + ch]);
    }
    return ((s0 + s1) + (s2 + s3)) + ((s4 + s5) + (s6 + s7));
}

// ---- Layer 1: gather, combine (fp16 r1), norm, relu, project ----
__global__ __launch_bounds__(256) void k_agg1(
    const int2* __restrict__ row2, const int* __restrict__ eid,
    const __half* __restrict__ y1, const __half* __restrict__ r1,
    const float* __restrict__ W2l, const float* __restrict__ W2r,
    const float* __restrict__ b2,
    __half* __restrict__ z2, __half* __restrict__ r2, int n_nodes)
{
    int t = blockIdx.x * 256 + threadIdx.x;
    int n = t >> 5;
    int ch = t & 31;
    if (n >= n_nodes) return;
    int2 be = row2[n];
    float sum = gather_sum(eid, y1, be.x, be.y, ch);
    float inv = 1.0f / fmaxf((float)(be.y - be.x), 1.0f);
    float v = fmaf(sum, inv, __half2float(r1[(size_t)n * 32 + ch]));
    float ss = v * v;
#pragma unroll
    for (int off = 16; off >= 1; off >>= 1) ss += __shfl_xor(ss, off, 32);
    float h = fmaxf(v / fmaxf(sqrtf(ss), 1e-12f), 0.f);
    float accl = 0.f, accr = 0.f;
#pragma unroll 4
    for (int ii = 0; ii < 32; ++ii) {
        float hv = __shfl(h, ii, 32);
        if (ch < 20) {
            accl = fmaf(hv, W2l[ii * 20 + ch], accl);
            accr = fmaf(hv, W2r[ii * 20 + ch], accr);
        }
    }
    z2[(size_t)n * 32 + ch] = __float2half(ch < 20 ? accl : 0.f);
    r2[(size_t)n * 32 + ch] = __float2half(ch < 20 ? accr + b2[ch] : 0.f);
}

// ---- Layer 2: gather, combine (fp16 r2), norm, W_out, softmax ----
__global__ __launch_bounds__(256) void k_agg2(
    const int2* __restrict__ row2, const int* __restrict__ eid,
    const __half* __restrict__ z2, const __half* __restrict__ r2,
    const float* __restrict__ Wout, const float* __restrict__ bout,
    float* __restrict__ out, int n_nodes)
{
    int t = blockIdx.x * 256 + threadIdx.x;
    int n = t >> 5;
    int ch = t & 31;
    if (n >= n_nodes) return;
    int2 be = row2[n];
    bool act = ch < 20;
    float sum = gather_sum(eid, z2, be.x, be.y, ch);
    float inv = 1.0f / fmaxf((float)(be.y - be.x), 1.0f);
    float v = act ? fmaf(sum, inv, __half2float(r2[(size_t)n * 32 + ch])) : 0.f;
    float ss = v * v;
#pragma unroll
    for (int off = 16; off >= 1; off >>= 1) ss += __shfl_xor(ss, off, 32);
    float o = v / fmaxf(sqrtf(ss), 1e-12f);
    float acc = (ch < 10) ? bout[ch] : 0.f;
#pragma unroll 4
    for (int ii = 0; ii < 20; ++ii) {
        float ov = __shfl(o, ii, 32);
        if (ch < 10) acc = fmaf(ov, Wout[ii * 10 + ch], acc);
    }
    float lm = (ch < 10) ? acc : -1e30f;
    float m = lm;
#pragma unroll
    for (int off = 8; off >= 1; off >>= 1) m = fmaxf(m, __shfl_xor(m, off, 16));
    float ex = (ch < 10) ? expf(acc - m) : 0.f;
    float s2r = ex;
#pragma unroll
    for (int off = 8; off >= 1; off >>= 1) s2r += __shfl_xor(s2r, off, 16);
    if (ch < 10) out[(size_t)n * 10 + ch] = ex / s2r;
}

extern "C" void kernel_launch(void* const* d_in, const int* in_sizes, int n_in,
                              void* d_out, int out_size, void* d_ws, size_t ws_size,
                              hipStream_t stream)
{
    const float* x    = (const float*)d_in[0];
    const int*   ei   = (const int*)d_in[1];
    const float* W1l  = (const float*)d_in[2];
    const float* b1   = (const float*)d_in[3];
    const float* W1r  = (const float*)d_in[4];
    const float* W2l  = (const float*)d_in[5];
    const float* b2   = (const float*)d_in[6];
    const float* W2r  = (const float*)d_in[7];
    const float* Wout = (const float*)d_in[8];
    const float* bout = (const float*)d_in[9];
    float* out = (float*)d_out;

    int n_nodes = in_sizes[0] / 128;
    int n_edges = in_sizes[1] / 2;
    const int* src = ei;
    const int* dst = ei + n_edges;

    int nb = (n_nodes + BS_NODES - 1) / BS_NODES;   // 782 (<= 1024)
    double mean = (double)n_edges / nb;
    int capb = (int)(mean + 8.0 * sqrt(mean) + 64.0);
    capb = (capb + 63) & ~63;

    // workspace: bcursor | row2 | pairs | eid | y1 | r1 ; z2/r2 alias pairs
    int*  bcursor = (int*)d_ws;                         // nb (memset to 0)
    int2* row2    = (int2*)((char*)d_ws + (((size_t)nb * 4 + 15) & ~(size_t)15)); // N int2
    int*  pairs   = (int*)(row2 + n_nodes);             // nb*capb
    size_t npairs = ((size_t)nb * capb + 3) & ~(size_t)3;
    int*  eid     = pairs + npairs;                     // nb*capb
    __half* y1 = (__half*)(eid + npairs);               // N*32 halfs
    __half* r1 = y1 + (size_t)n_nodes * 32;             // N*32 halfs (b1 folded)
    __half* z2 = (__half*)pairs;                        // alias: pairs dead after bfill
    __half* r2 = z2 + (size_t)n_nodes * 32;             // N*32 halfs (b2 folded)

    int nb_part = (n_edges + PART_TILE - 1) / PART_TILE;  // 391
    int nbl     = (n_nodes + 255) / 256;                  // 391
    int nb_grp  = ((n_nodes * 32) + 255) / 256;

    (void)hipMemsetAsync(bcursor, 0, (size_t)nb * sizeof(int), stream);
    k_partlin<<<nb_part + nbl, 256, 0, stream>>>(
        src, dst, bcursor, pairs, x, W1l, b1, W1r, y1, r1,
        n_edges, nb, capb, n_nodes, nb_part);
    k_bfill<<<nb, 256, 0, stream>>>(pairs, bcursor, row2, eid, capb, n_nodes);
    k_agg1<<<nb_grp, 256, 0, stream>>>(row2, eid, y1, r1, W2l, W2r, b2, z2, r2, n_nodes);
    k_agg2<<<nb_grp, 256, 0, stream>>>(row2, eid, z2, r2, Wout, bout, out, n_nodes);
}